// Round 20
// baseline (157.844 us; speedup 1.0000x reference)
//
#include <hip/hip_runtime.h>
#include <stdint.h>

#define NN 100000   // nodes
#define NREL 3
#define NE 200000   // edges per relation
#define F 128       // feature dim (in = hid = out)
#define NQ 4096

#define NBUCK (NREL * NN)              // 300000 fine buckets (rel*NN + node)
#define NCB ((NBUCK + 255) / 256)      // 1172 coarse bins (fine >> 8)
#define CH_BLOCKS 128
#define CH_CHUNK ((NREL * NE + CH_BLOCKS - 1) / CH_BLOCKS)   // 4688

// prep index-space partition (merged kernel: blocks >= PREP_BLKS run coarseHH)
#define WCVT_N (2 * NREL * F * F)      // 98304
#define A1 (WCVT_N + 256)              // bias end
#define A2 (A1 + NN * F / 8)           // cvtx end
#define A3 (A2 + 2 * NQ)               // qnode end
#define A4 (A3 + NN)                   // mark zero end
#define A5 (A4 + NN)                   // qflag zero end
#define PREP_N (A5 + 1)                // +cursor
#define PREP_BLKS ((PREP_N + 255) / 256)

typedef float fx4 __attribute__((ext_vector_type(4)));
typedef unsigned short u16x8 __attribute__((ext_vector_type(8)));
typedef __bf16 bf16x8 __attribute__((ext_vector_type(8)));

__device__ __forceinline__ unsigned short f2bf(float f) {
  uint32_t u = __builtin_bit_cast(uint32_t, f);
  uint32_t r = u + 0x7FFFu + ((u >> 16) & 1u);
  return (unsigned short)(r >> 16);
}
__device__ __forceinline__ float bf2f(unsigned short u) {
  return __builtin_bit_cast(float, (uint32_t)u << 16);
}
__device__ __forceinline__ int rel_of(int i) {  // i in [0, 3*NE)
  return (i >= 2 * NE) ? 2 : (i >= NE ? 1 : 0);
}

// ---- merged prep + dual coarse histogram (independent work, block-range split) ----
// H layout: [blk][bin] -> histogram writes coalesced; strided readers hit L2 (2.4MB).
__global__ __launch_bounds__(256) void prepch_kernel(
    const float* __restrict__ W1, const float* __restrict__ W2,
    const float* __restrict__ b1, const float* __restrict__ b2,
    const float* __restrict__ emb,
    const int* __restrict__ qsrc, const int* __restrict__ qdst,
    const int* __restrict__ es, const int* __restrict__ ed,
    unsigned short* __restrict__ Wtb, float* __restrict__ bsum,
    unsigned short* __restrict__ xb,
    int* __restrict__ qnode, int* __restrict__ mark, int* __restrict__ qflag,
    int* __restrict__ cursor,
    int* __restrict__ Hd, int* __restrict__ Hs) {
  __shared__ int hd[NCB], hs[NCB];
  int t = threadIdx.x;
  if (blockIdx.x >= PREP_BLKS) {
    // ---- coarseHH part ----
    int blk = blockIdx.x - PREP_BLKS;
    for (int j = t; j < NCB; j += 256) { hd[j] = 0; hs[j] = 0; }
    __syncthreads();
    int lo = blk * CH_CHUNK;
    int hi = min(lo + CH_CHUNK, NREL * NE);
    for (int i = lo + t; i < hi; i += 256) {
      int r = rel_of(i);
      atomicAdd(&hd[(r * NN + ed[i]) >> 8], 1);
      atomicAdd(&hs[(r * NN + es[i]) >> 8], 1);
    }
    __syncthreads();
    for (int j = t; j < NCB; j += 256) {     // coalesced row write
      Hd[blk * NCB + j] = hd[j];
      Hs[blk * NCB + j] = hs[j];
    }
    return;
  }
  // ---- prep part ----
  int i = blockIdx.x * blockDim.x + t;
  if (i < WCVT_N) {
    int l = i / (NREL * F * F);
    int rem = i % (NREL * F * F);
    int r = rem / (F * F);
    int nk = rem % (F * F);
    int n = nk >> 7, k = nk & 127;
    const float* W = l ? W2 : W1;
    Wtb[i] = f2bf(W[r * F * F + k * F + n]);
  } else if (i < A1) {
    int tt = i - WCVT_N;
    int l = tt >> 7, f = tt & 127;
    const float* b = l ? b2 : b1;
    bsum[l * F + f] = b[f] + b[F + f] + b[2 * F + f];
  } else if (i < A2) {
    int j = i - A1;
    const float* p = emb + (size_t)j * 8;
    unsigned short tmp[8];
#pragma unroll
    for (int e = 0; e < 8; ++e) tmp[e] = f2bf(p[e]);
    *reinterpret_cast<u16x8*>(xb + (size_t)j * 8) = *reinterpret_cast<u16x8*>(tmp);
  } else if (i < A3) {
    int m = i - A2;
    qnode[m] = (m < NQ) ? qsrc[m] : qdst[m - NQ];
  } else if (i < A4) {
    mark[i - A3] = 0;
  } else if (i < A5) {
    qflag[i - A4] = 0;
  } else if (i < PREP_N) {
    *cursor = 0;
  }
}

// ---- scan: per-bin totals (summed from H directly) + exclusive scan ----
// block 0 = dst axis, block 1 = src axis, block 2 = qflag set. (hsum folded in)
__global__ __launch_bounds__(256) void cscan_kernel(const int* __restrict__ Hd,
                                                    const int* __restrict__ Hs,
                                                    const int* __restrict__ qnode,
                                                    int* __restrict__ chist_d,
                                                    int* __restrict__ chist_s,
                                                    int* __restrict__ cstart_d,
                                                    int* __restrict__ cstart_s,
                                                    int* __restrict__ qflag) {
  int t = threadIdx.x, lane = t & 63, w = t >> 6;
  if (blockIdx.x == 2) {
    for (int q = t; q < 2 * NQ; q += 256) qflag[qnode[q]] = 1;
    return;
  }
  const int* H = blockIdx.x ? Hs : Hd;
  int* chist = blockIdx.x ? chist_s : chist_d;
  int* cstart = blockIdx.x ? cstart_s : cstart_d;
  int v[5];
  int s = 0;
#pragma unroll
  for (int k = 0; k < 5; ++k) {
    int i = t * 5 + k;
    int sum = 0;
    if (i < NCB) {
      for (int b = 0; b < CH_BLOCKS; ++b) sum += H[(size_t)b * NCB + i];
      chist[i] = sum;
    }
    v[k] = sum;
    s += sum;
  }
  int sc = s;
#pragma unroll
  for (int d = 1; d < 64; d <<= 1) {
    int o = __shfl_up(sc, d);
    if (lane >= d) sc += o;
  }
  __shared__ int wt[4];
  if (lane == 63) wt[w] = sc;
  __syncthreads();
  int woff = 0;
#pragma unroll
  for (int ww = 0; ww < 3; ++ww) woff += (ww < w) ? wt[ww] : 0;
  int excl = woff + sc - s;
#pragma unroll
  for (int k = 0; k < 5; ++k) {
    int i = t * 5 + k;
    if (i < NCB) { cstart[i] = excl; excl += v[k]; }
  }
}

// ---- per-(bin,block) bases: wave scans its bin's 128 counts ----
__global__ __launch_bounds__(256) void hbase_kernel(const int* __restrict__ Hd,
                                                    const int* __restrict__ Hs,
                                                    const int* __restrict__ cstart_d,
                                                    const int* __restrict__ cstart_s,
                                                    int* __restrict__ Hbase_d,
                                                    int* __restrict__ Hbase_s) {
  const int* H = blockIdx.y ? Hs : Hd;
  const int* cstart = blockIdx.y ? cstart_s : cstart_d;
  int* Hbase = blockIdx.y ? Hbase_s : Hbase_d;
  int t = threadIdx.x, lane = t & 63;
  int bin = blockIdx.x * 4 + (t >> 6);   // 293*4 = 1172 exact
  int v[2];
  int s = 0;
#pragma unroll
  for (int k = 0; k < 2; ++k) {
    v[k] = H[(size_t)(lane * 2 + k) * NCB + bin];
    s += v[k];
  }
  int sc = s;
#pragma unroll
  for (int d = 1; d < 64; d <<= 1) {
    int o = __shfl_up(sc, d);
    if (lane >= d) sc += o;
  }
  int run = cstart[bin] + sc - s;
#pragma unroll
  for (int k = 0; k < 2; ++k) {
    Hbase[bin * CH_BLOCKS + lane * 2 + k] = run;
    run += v[k];
  }
}

// ---- dual coarse scatter, atomic-free (two block-private LDS cursor sets) ----
__global__ __launch_bounds__(256) void cscatter_kernel(const int* __restrict__ es,
                                                       const int* __restrict__ ed,
                                                       const int* __restrict__ Hbase_d,
                                                       const int* __restrict__ Hbase_s,
                                                       int* __restrict__ etmp_d,
                                                       int* __restrict__ etmp_s) {
  __shared__ int cur_d[NCB], cur_s[NCB];
  int t = threadIdx.x, blk = blockIdx.x;
  for (int j = t; j < NCB; j += 256) {
    cur_d[j] = Hbase_d[j * CH_BLOCKS + blk];
    cur_s[j] = Hbase_s[j * CH_BLOCKS + blk];
  }
  __syncthreads();
  int lo = blk * CH_CHUNK;
  int hi = min(lo + CH_CHUNK, NREL * NE);
  for (int i = lo + t; i < hi; i += 256) {
    int r = rel_of(i);
    int s = es[i], d = ed[i];
    int bd = r * NN + d;
    int pos = atomicAdd(&cur_d[bd >> 8], 1);
    etmp_d[pos] = (s << 8) | (bd & 255);
    int bs = r * NN + s;
    int pos_s = atomicAdd(&cur_s[bs >> 8], 1);
    etmp_s[pos_s] = bs & 255;
  }
}

// ---- src fine count: dense cnt_src write, no atomics beyond LDS ----
__global__ __launch_bounds__(256) void srccount_kernel(const int* __restrict__ etmp_s,
                                                       const int* __restrict__ cstart_s,
                                                       const int* __restrict__ chist_s,
                                                       int* __restrict__ cnt_src) {
  const int cb = blockIdx.x;
  const int t = threadIdx.x;
  const int cs = cstart_s[cb], cc = chist_s[cb];
  __shared__ int fcnt[256];
  fcnt[t] = 0;
  __syncthreads();
  for (int i = t; i < cc; i += 256) atomicAdd(&fcnt[etmp_s[cs + i]], 1);
  __syncthreads();
  int b = cb * 256 + t;
  if (b < NBUCK) cnt_src[b] = fcnt[t];
}

// ---- fine pass (dst) + integrated h1-source marking ----
__global__ __launch_bounds__(256) void fine_kernel(const int* __restrict__ etmp,
                                                   const int* __restrict__ cstart,
                                                   const int* __restrict__ chist,
                                                   const int* __restrict__ cnt_src,
                                                   const int* __restrict__ qflag,
                                                   int2* __restrict__ scb,
                                                   int2* __restrict__ epay,
                                                   int* __restrict__ mark) {
  const int cb = blockIdx.x;
  const int t = threadIdx.x, lane = t & 63, w = t >> 6;
  const int cs = cstart[cb], cc = chist[cb];
  __shared__ int fcnt[256], fexcl[256], fcur[256];
  fcnt[t] = 0;
  fcur[t] = 0;
  __syncthreads();
  for (int i = t; i < cc; i += 256) atomicAdd(&fcnt[etmp[cs + i] & 255], 1);
  __syncthreads();
  int val = fcnt[t];
  int sc = val;
#pragma unroll
  for (int d = 1; d < 64; d <<= 1) {
    int o = __shfl_up(sc, d);
    if (lane >= d) sc += o;
  }
  __shared__ int wt[4];
  if (lane == 63) wt[w] = sc;
  __syncthreads();
  int woff = 0;
#pragma unroll
  for (int ww = 0; ww < 3; ++ww) woff += (ww < w) ? wt[ww] : 0;
  fexcl[t] = woff + sc - val;
  int b = cb * 256 + t;
  if (b < NBUCK) scb[b] = make_int2(cs + fexcl[t], val);
  __syncthreads();
  for (int i = t; i < cc; i += 256) {
    int e = etmp[cs + i];
    int f = e & 255;
    int src = ((unsigned)e) >> 8;
    int fine = cb * 256 + f;
    int r = fine / NN;
    int dst = fine - r * NN;
    float wgt = rsqrtf((float)cnt_src[r * NN + src]) * rsqrtf((float)fcnt[f]);
    int pos = cs + fexcl[f] + atomicAdd(&fcur[f], 1);
    epay[pos] = make_int2(src, __builtin_bit_cast(int, wgt));
    if (qflag[dst]) mark[src] = 1;   // h1 needed at this source (idempotent store)
  }
}

// ---- compact marked nodes -> list (one atomic per 1024-elem block) ----
__global__ __launch_bounds__(256) void compact_kernel(const int* __restrict__ mark,
                                                      int* __restrict__ list,
                                                      int* __restrict__ cursor) {
  int t = threadIdx.x, lane = t & 63, w = t >> 6;
  int base = blockIdx.x * 1024 + t * 4;
  int loc[4];
  int cnt = 0;
#pragma unroll
  for (int k = 0; k < 4; ++k) {
    int i = base + k;
    if (i < NN && mark[i]) { loc[cnt] = i; ++cnt; }
  }
  int sc = cnt;
#pragma unroll
  for (int d = 1; d < 64; d <<= 1) {
    int o = __shfl_up(sc, d);
    if (lane >= d) sc += o;
  }
  int texcl = sc - cnt;
  __shared__ int wt[4];
  __shared__ int bb;
  if (lane == 63) wt[w] = sc;
  __syncthreads();
  if (t == 0) {
    int tot = wt[0] + wt[1] + wt[2] + wt[3];
    bb = atomicAdd(cursor, tot);
    int a = 0;
#pragma unroll
    for (int ww = 0; ww < 4; ++ww) { int c = wt[ww]; wt[ww] = a; a += c; }
  }
  __syncthreads();
  int p = bb + wt[w] + texcl;
  for (int k = 0; k < cnt; ++k) list[p + k] = loc[k];
}

// ---- aggregate: Z[r][m][f] = sum_{e in bucket(r, nmap[m])} w_e * X[src_e][f] ----
__global__ __launch_bounds__(256) void aggz_kernel(const unsigned short* __restrict__ X,
                                                   const int2* __restrict__ scb,
                                                   const int2* __restrict__ epay,
                                                   const int* __restrict__ nmap,
                                                   const int* __restrict__ cntp,
                                                   unsigned short* __restrict__ Z,
                                                   int Mcap, int Ms) {
  const int count = cntp ? *cntp : Mcap;
  const int r = blockIdx.y;
  const int t = threadIdx.x;
  const int lane = t & 63;
  const int m = blockIdx.x * 16 + (t >> 6) * 4 + (lane >> 4);
  const int j = lane & 15;
  if (m >= count) return;
  int n = nmap ? nmap[m] : m;
  int2 meta = scb[r * NN + n];
  const int2* ep = epay + meta.x;
  const int c = meta.y;

  float ps[8];
#pragma unroll
  for (int k = 0; k < 8; ++k) ps[k] = 0.f;

  int i = 0;
  for (; i + 2 <= c; i += 2) {
    int2 p0 = ep[i], p1 = ep[i + 1];
    float w0 = __builtin_bit_cast(float, p0.y);
    float w1 = __builtin_bit_cast(float, p1.y);
    u16x8 v0 = *reinterpret_cast<const u16x8*>(X + ((size_t)p0.x << 7) + j * 8);
    u16x8 v1 = *reinterpret_cast<const u16x8*>(X + ((size_t)p1.x << 7) + j * 8);
#pragma unroll
    for (int k = 0; k < 8; ++k)
      ps[k] = fmaf(bf2f(v1[k]), w1, fmaf(bf2f(v0[k]), w0, ps[k]));
  }
  if (i < c) {
    int2 p0 = ep[i];
    float w0 = __builtin_bit_cast(float, p0.y);
    u16x8 v0 = *reinterpret_cast<const u16x8*>(X + ((size_t)p0.x << 7) + j * 8);
#pragma unroll
    for (int k = 0; k < 8; ++k) ps[k] = fmaf(bf2f(v0[k]), w0, ps[k]);
  }

  unsigned short tmp[8];
#pragma unroll
  for (int k = 0; k < 8; ++k) tmp[k] = f2bf(ps[k]);
  *reinterpret_cast<u16x8*>(Z + (((size_t)r * Ms + m) << 7) + j * 8) =
      *reinterpret_cast<u16x8*>(tmp);
}

// ---- K=384 GEMM: global_load_lds staging + 2-phase pipeline (R11-proven) ----
#define GBM 128
__global__ __launch_bounds__(512) void gemmp_kernel(const unsigned short* __restrict__ Z,
                                                    const unsigned short* __restrict__ Wt3,
                                                    const float* __restrict__ bsum,
                                                    const int* __restrict__ omap,
                                                    const int* __restrict__ cntp,
                                                    void* __restrict__ outp,
                                                    int M, int Ms, int out_f32) {
  const int count = cntp ? *cntp : M;
  const int m0 = blockIdx.x * GBM;
  if (m0 >= count) return;
  __shared__ unsigned short Abuf[2][GBM * F];   // 2 x 32 KB
  const int t = threadIdx.x;
  const int lane = t & 63, w = t >> 6;
  const int wm = w >> 2, wn = w & 3;            // 2m x 4n wave grid
  const int r0 = lane & 15, kq = lane >> 4;

  fx4 acc[4][2];
#pragma unroll
  for (int mt = 0; mt < 4; ++mt)
#pragma unroll
    for (int nt = 0; nt < 2; ++nt) acc[mt][nt] = (fx4){0.f, 0.f, 0.f, 0.f};

  {
    const unsigned short* Zr = Z + (size_t)m0 * F;
#pragma unroll
    for (int i = 0; i < 4; ++i) {
      int slot = i * 512 + t;
      int row = slot >> 4, s = slot & 15;
      __builtin_amdgcn_global_load_lds(
          (const __attribute__((address_space(1))) uint32_t*)(
              Zr + ((size_t)row << 7) + ((s ^ (row & 7)) << 3)),
          (__attribute__((address_space(3))) uint32_t*)&Abuf[0][slot * 8], 16, 0, 0);
    }
  }
  __syncthreads();

  int cur = 0;
  for (int r = 0; r < NREL; ++r) {
    bf16x8 bfrag[2][4];
    const unsigned short* Wt = Wt3 + (size_t)r * F * F;
#pragma unroll
    for (int nt = 0; nt < 2; ++nt)
#pragma unroll
      for (int kb = 0; kb < 4; ++kb)
        bfrag[nt][kb] = __builtin_bit_cast(bf16x8,
            *reinterpret_cast<const u16x8*>(
                Wt + (wn * 32 + nt * 16 + r0) * F + (4 * kb + kq) * 8));

    if (r + 1 < NREL) {
      const unsigned short* Zr = Z + ((size_t)(r + 1) * Ms + m0) * F;
#pragma unroll
      for (int i = 0; i < 4; ++i) {
        int slot = i * 512 + t;
        int row = slot >> 4, s = slot & 15;
        __builtin_amdgcn_global_load_lds(
            (const __attribute__((address_space(1))) uint32_t*)(
                Zr + ((size_t)row << 7) + ((s ^ (row & 7)) << 3)),
            (__attribute__((address_space(3))) uint32_t*)&Abuf[cur ^ 1][slot * 8],
            16, 0, 0);
      }
    }

#pragma unroll
    for (int kb = 0; kb < 4; ++kb) {
      const int cs = ((kb * 4 + kq) ^ (r0 & 7)) * 8;
      bf16x8 a[4];
#pragma unroll
      for (int mt = 0; mt < 4; ++mt)
        a[mt] = __builtin_bit_cast(bf16x8,
            *reinterpret_cast<const u16x8*>(&Abuf[cur][(wm * 64 + mt * 16 + r0) * F + cs]));
#pragma unroll
      for (int mt = 0; mt < 4; ++mt)
#pragma unroll
        for (int nt = 0; nt < 2; ++nt)
          acc[mt][nt] = __builtin_amdgcn_mfma_f32_16x16x32_bf16(a[mt], bfrag[nt][kb],
                                                                acc[mt][nt], 0, 0, 0);
    }

    __syncthreads();
    cur ^= 1;
  }

#pragma unroll
  for (int mt = 0; mt < 4; ++mt) {
    const int rbase = m0 + wm * 64 + mt * 16 + kq * 4;
#pragma unroll
    for (int nt = 0; nt < 2; ++nt) {
      int col = wn * 32 + nt * 16 + r0;
      float bb = bsum[col];
#pragma unroll
      for (int reg = 0; reg < 4; ++reg) {
        int gm = rbase + reg;
        if (gm < count) {
          float v = tanhf(acc[mt][nt][reg] + bb);
          if (omap) {
            ((unsigned short*)outp)[(size_t)omap[gm] * F + col] = f2bf(v);
          } else if (out_f32) {
            ((float*)outp)[(size_t)gm * F + col] = v;
          } else {
            ((unsigned short*)outp)[(size_t)gm * F + col] = f2bf(v);
          }
        }
      }
    }
  }
}

extern "C" void kernel_launch(void* const* d_in, const int* in_sizes, int n_in,
                              void* d_out, int out_size, void* d_ws, size_t ws_size,
                              hipStream_t stream) {
  const float* emb = (const float*)d_in[0];
  const float* W1  = (const float*)d_in[1];
  const float* b1  = (const float*)d_in[2];
  const float* W2  = (const float*)d_in[3];
  const float* b2  = (const float*)d_in[4];
  const int* e_src = (const int*)d_in[5];
  const int* e_dst = (const int*)d_in[6];
  const int* qsrc  = (const int*)d_in[7];
  const int* qdst  = (const int*)d_in[8];
  float* out = (float*)d_out;

  const int MS1 = ((NN + GBM - 1) / GBM) * GBM;   // 100096 (Z stride/capacity, layer 1)
  const int MQ  = 2 * NQ;                          // 8192

  char* p = (char*)d_ws;
  size_t off = 0;
  auto take = [&](size_t n) { void* q = p + off; off = (off + n + 255) & ~(size_t)255; return q; };
  int* cnt_src  = (int*)take((size_t)NREL * NN * 4);
  int* chist_d  = (int*)take((size_t)NCB * 4);
  int* chist_s  = (int*)take((size_t)NCB * 4);
  int* cstart_d = (int*)take((size_t)NCB * 4);
  int* cstart_s = (int*)take((size_t)NCB * 4);
  int* Hd       = (int*)take((size_t)NCB * CH_BLOCKS * 4);
  int* Hs       = (int*)take((size_t)NCB * CH_BLOCKS * 4);
  int* Hbase_d  = (int*)take((size_t)NCB * CH_BLOCKS * 4);
  int* Hbase_s  = (int*)take((size_t)NCB * CH_BLOCKS * 4);
  int* etmp_d   = (int*)take((size_t)NREL * NE * 4);
  int* etmp_s   = (int*)take((size_t)NREL * NE * 4);
  int2* scb     = (int2*)take((size_t)NBUCK * 8);
  int2* epay    = (int2*)take((size_t)NREL * NE * 8);
  unsigned short* Wtb = (unsigned short*)take(2ull * NREL * F * F * 2);
  float* bsum   = (float*)take(2ull * F * 4);
  int* qnode    = (int*)take((size_t)MQ * 4);
  int* mark     = (int*)take((size_t)NN * 4);
  int* qflag    = (int*)take((size_t)NN * 4);
  int* list     = (int*)take((size_t)NN * 4 + 4);
  int* cursor   = (int*)take(4);
  unsigned short* Xb  = (unsigned short*)take((size_t)NN * F * 2);   // h0 (bf16)
  unsigned short* Xb2 = (unsigned short*)take((size_t)NN * F * 2);   // h1 (bf16, by node id)
  unsigned short* Z   = (unsigned short*)take((size_t)NREL * MS1 * F * 2);

  // 1: merged prep + coarse histograms
  prepch_kernel<<<PREP_BLKS + CH_BLOCKS, 256, 0, stream>>>(
      W1, W2, b1, b2, emb, qsrc, qdst, e_src, e_dst,
      Wtb, bsum, Xb, qnode, mark, qflag, cursor, Hd, Hs);
  // 2-5: atomic-free dual radix bucket build (hsum folded into cscan; +qflag block)
  cscan_kernel<<<3, 256, 0, stream>>>(Hd, Hs, qnode, chist_d, chist_s,
                                      cstart_d, cstart_s, qflag);
  {
    dim3 hb(NCB / 4, 2);
    hbase_kernel<<<hb, 256, 0, stream>>>(Hd, Hs, cstart_d, cstart_s, Hbase_d, Hbase_s);
  }
  cscatter_kernel<<<CH_BLOCKS, 256, 0, stream>>>(e_src, e_dst, Hbase_d, Hbase_s,
                                                 etmp_d, etmp_s);
  srccount_kernel<<<NCB, 256, 0, stream>>>(etmp_s, cstart_s, chist_s, cnt_src);
  // 6: fine placement + h1-source marking
  fine_kernel<<<NCB, 256, 0, stream>>>(etmp_d, cstart_d, chist_d, cnt_src, qflag,
                                       scb, epay, mark);
  // 7: compact marked nodes
  compact_kernel<<<(NN + 1023) / 1024, 256, 0, stream>>>(mark, list, cursor);

  // 8-9: layer 1 on listed nodes only; h1 scattered to Xb2 by node id
  dim3 ag1((NN + 15) / 16, NREL);
  aggz_kernel<<<ag1, 256, 0, stream>>>(Xb, scb, epay, list, cursor, Z, NN, MS1);
  gemmp_kernel<<<MS1 / GBM, 512, 0, stream>>>(Z, Wtb, bsum, list, cursor, Xb2, MS1, MS1, 0);

  // 10-11: layer 2 on the 2*NQ query slots
  dim3 ag2((MQ + 15) / 16, NREL);
  aggz_kernel<<<ag2, 256, 0, stream>>>(Xb2, scb, epay, qnode, nullptr, Z, MQ, MQ);
  gemmp_kernel<<<MQ / GBM, 512, 0, stream>>>(
      Z, Wtb + (size_t)NREL * F * F, bsum + F, nullptr, nullptr, out, MQ, MQ, 1);
}

// Round 21
// 148.376 us; speedup vs baseline: 1.0638x; 1.0638x over previous
//
#include <hip/hip_runtime.h>
#include <stdint.h>

#define NN 100000   // nodes
#define NREL 3
#define NE 200000   // edges per relation
#define F 128       // feature dim (in = hid = out)
#define NQ 4096

#define NBUCK (NREL * NN)              // 300000 fine buckets (rel*NN + node)
#define NCB ((NBUCK + 255) / 256)      // 1172 coarse bins (fine >> 8)
#define CH_BLOCKS 512
#define CH_CHUNK ((NREL * NE + CH_BLOCKS - 1) / CH_BLOCKS)   // 1172

// prep index-space partition (merged kernel: blocks >= PREP_BLKS run coarseHH)
#define WCVT_N (2 * NREL * F * F)      // 98304
#define A1 (WCVT_N + 256)              // bias end
#define A2 (A1 + NN * F / 8)           // cvtx end
#define A3 (A2 + 2 * NQ)               // qnode end
#define A4 (A3 + NN)                   // mark zero end
#define A5 (A4 + NN)                   // qflag zero end
#define PREP_N (A5 + 1)                // +cursor
#define PREP_BLKS ((PREP_N + 255) / 256)

typedef float fx4 __attribute__((ext_vector_type(4)));
typedef unsigned short u16x8 __attribute__((ext_vector_type(8)));
typedef __bf16 bf16x8 __attribute__((ext_vector_type(8)));

__device__ __forceinline__ unsigned short f2bf(float f) {
  uint32_t u = __builtin_bit_cast(uint32_t, f);
  uint32_t r = u + 0x7FFFu + ((u >> 16) & 1u);
  return (unsigned short)(r >> 16);
}
__device__ __forceinline__ float bf2f(unsigned short u) {
  return __builtin_bit_cast(float, (uint32_t)u << 16);
}
__device__ __forceinline__ int rel_of(int i) {  // i in [0, 3*NE)
  return (i >= 2 * NE) ? 2 : (i >= NE ? 1 : 0);
}

// ---- merged prep + dual coarse histogram (independent work, block-range split) ----
// H layout: [blk][bin] -> histogram writes are COALESCED; strided reads in
// hsum/hbase are L2/L3-absorbed (H = 9.6MB total).
__global__ __launch_bounds__(256) void prepch_kernel(
    const float* __restrict__ W1, const float* __restrict__ W2,
    const float* __restrict__ b1, const float* __restrict__ b2,
    const float* __restrict__ emb,
    const int* __restrict__ qsrc, const int* __restrict__ qdst,
    const int* __restrict__ es, const int* __restrict__ ed,
    unsigned short* __restrict__ Wtb, float* __restrict__ bsum,
    unsigned short* __restrict__ xb,
    int* __restrict__ qnode, int* __restrict__ mark, int* __restrict__ qflag,
    int* __restrict__ cursor,
    int* __restrict__ Hd, int* __restrict__ Hs) {
  __shared__ int hd[NCB], hs[NCB];
  int t = threadIdx.x;
  if (blockIdx.x >= PREP_BLKS) {
    // ---- coarseHH part ----
    int blk = blockIdx.x - PREP_BLKS;
    for (int j = t; j < NCB; j += 256) { hd[j] = 0; hs[j] = 0; }
    __syncthreads();
    int lo = blk * CH_CHUNK;
    int hi = min(lo + CH_CHUNK, NREL * NE);
    for (int i = lo + t; i < hi; i += 256) {
      int r = rel_of(i);
      atomicAdd(&hd[(r * NN + ed[i]) >> 8], 1);
      atomicAdd(&hs[(r * NN + es[i]) >> 8], 1);
    }
    __syncthreads();
    for (int j = t; j < NCB; j += 256) {     // coalesced row write
      Hd[blk * NCB + j] = hd[j];
      Hs[blk * NCB + j] = hs[j];
    }
    return;
  }
  // ---- prep part ----
  int i = blockIdx.x * blockDim.x + t;
  if (i < WCVT_N) {
    int l = i / (NREL * F * F);
    int rem = i % (NREL * F * F);
    int r = rem / (F * F);
    int nk = rem % (F * F);
    int n = nk >> 7, k = nk & 127;
    const float* W = l ? W2 : W1;
    Wtb[i] = f2bf(W[r * F * F + k * F + n]);
  } else if (i < A1) {
    int tt = i - WCVT_N;
    int l = tt >> 7, f = tt & 127;
    const float* b = l ? b2 : b1;
    bsum[l * F + f] = b[f] + b[F + f] + b[2 * F + f];
  } else if (i < A2) {
    int j = i - A1;
    const float* p = emb + (size_t)j * 8;
    unsigned short tmp[8];
#pragma unroll
    for (int e = 0; e < 8; ++e) tmp[e] = f2bf(p[e]);
    *reinterpret_cast<u16x8*>(xb + (size_t)j * 8) = *reinterpret_cast<u16x8*>(tmp);
  } else if (i < A3) {
    int m = i - A2;
    qnode[m] = (m < NQ) ? qsrc[m] : qdst[m - NQ];
  } else if (i < A4) {
    mark[i - A3] = 0;
  } else if (i < A5) {
    qflag[i - A4] = 0;
  } else if (i < PREP_N) {
    *cursor = 0;
  }
}

// ---- per-bin totals + qflag set; H reads strided ([blk][bin]), cache-absorbed ----
__global__ __launch_bounds__(256) void hsum_kernel(const int* __restrict__ Hd,
                                                   const int* __restrict__ Hs,
                                                   const int* __restrict__ qnode,
                                                   int* __restrict__ chist_d,
                                                   int* __restrict__ chist_s,
                                                   int* __restrict__ qflag) {
  int t = threadIdx.x, lane = t & 63;
  int q = blockIdx.x * 256 + t;
  if (q < 2 * NQ) qflag[qnode[q]] = 1;
  int ws = blockIdx.x * 4 + (t >> 6);    // 0..2*NCB-1
  if (ws >= 2 * NCB) return;
  const int* H = (ws < NCB) ? Hd : Hs;
  int bin = (ws < NCB) ? ws : ws - NCB;
  int s = 0;
#pragma unroll
  for (int k = 0; k < 8; ++k) s += H[(size_t)(lane * 8 + k) * NCB + bin];
#pragma unroll
  for (int d = 1; d < 64; d <<= 1) s += __shfl_xor(s, d);
  if (lane == 0) {
    if (ws < NCB) chist_d[bin] = s; else chist_s[bin] = s;
  }
}

// ---- exclusive scan of 1172 coarse totals; block 0 = dst, block 1 = src ----
__global__ __launch_bounds__(256) void cscan_kernel(const int* __restrict__ chist_d,
                                                    const int* __restrict__ chist_s,
                                                    int* __restrict__ cstart_d,
                                                    int* __restrict__ cstart_s) {
  const int* chist = blockIdx.x ? chist_s : chist_d;
  int* cstart = blockIdx.x ? cstart_s : cstart_d;
  int t = threadIdx.x, lane = t & 63, w = t >> 6;
  int v[5];
  int s = 0;
#pragma unroll
  for (int k = 0; k < 5; ++k) {
    int i = t * 5 + k;
    v[k] = (i < NCB) ? chist[i] : 0;
    s += v[k];
  }
  int sc = s;
#pragma unroll
  for (int d = 1; d < 64; d <<= 1) {
    int o = __shfl_up(sc, d);
    if (lane >= d) sc += o;
  }
  __shared__ int wt[4];
  if (lane == 63) wt[w] = sc;
  __syncthreads();
  int woff = 0;
#pragma unroll
  for (int ww = 0; ww < 3; ++ww) woff += (ww < w) ? wt[ww] : 0;
  int excl = woff + sc - s;
#pragma unroll
  for (int k = 0; k < 5; ++k) {
    int i = t * 5 + k;
    if (i < NCB) { cstart[i] = excl; excl += v[k]; }
  }
}

// ---- per-(bin,block) bases: wave scans its bin's 512 counts ----
// H reads strided ([blk][bin], cached); Hbase writes coalesced ([bin][blk]).
__global__ __launch_bounds__(256) void hbase_kernel(const int* __restrict__ Hd,
                                                    const int* __restrict__ Hs,
                                                    const int* __restrict__ cstart_d,
                                                    const int* __restrict__ cstart_s,
                                                    int* __restrict__ Hbase_d,
                                                    int* __restrict__ Hbase_s) {
  const int* H = blockIdx.y ? Hs : Hd;
  const int* cstart = blockIdx.y ? cstart_s : cstart_d;
  int* Hbase = blockIdx.y ? Hbase_s : Hbase_d;
  int t = threadIdx.x, lane = t & 63;
  int bin = blockIdx.x * 4 + (t >> 6);   // 293*4 = 1172 exact
  int v[8];
  int s = 0;
#pragma unroll
  for (int k = 0; k < 8; ++k) {
    v[k] = H[(size_t)(lane * 8 + k) * NCB + bin];
    s += v[k];
  }
  int sc = s;
#pragma unroll
  for (int d = 1; d < 64; d <<= 1) {
    int o = __shfl_up(sc, d);
    if (lane >= d) sc += o;
  }
  int run = cstart[bin] + sc - s;
#pragma unroll
  for (int k = 0; k < 8; ++k) {
    Hbase[bin * CH_BLOCKS + lane * 8 + k] = run;
    run += v[k];
  }
}

// ---- dual coarse scatter, atomic-free (two block-private LDS cursor sets) ----
__global__ __launch_bounds__(256) void cscatter_kernel(const int* __restrict__ es,
                                                       const int* __restrict__ ed,
                                                       const int* __restrict__ Hbase_d,
                                                       const int* __restrict__ Hbase_s,
                                                       int* __restrict__ etmp_d,
                                                       int* __restrict__ etmp_s) {
  __shared__ int cur_d[NCB], cur_s[NCB];
  int t = threadIdx.x, blk = blockIdx.x;
  for (int j = t; j < NCB; j += 256) {
    cur_d[j] = Hbase_d[j * CH_BLOCKS + blk];
    cur_s[j] = Hbase_s[j * CH_BLOCKS + blk];
  }
  __syncthreads();
  int lo = blk * CH_CHUNK;
  int hi = min(lo + CH_CHUNK, NREL * NE);
  for (int i = lo + t; i < hi; i += 256) {
    int r = rel_of(i);
    int s = es[i], d = ed[i];
    int bd = r * NN + d;
    int pos = atomicAdd(&cur_d[bd >> 8], 1);
    etmp_d[pos] = (s << 8) | (bd & 255);
    int bs = r * NN + s;
    int pos_s = atomicAdd(&cur_s[bs >> 8], 1);
    etmp_s[pos_s] = bs & 255;
  }
}

// ---- src fine count: dense cnt_src write, no atomics beyond LDS ----
__global__ __launch_bounds__(256) void srccount_kernel(const int* __restrict__ etmp_s,
                                                       const int* __restrict__ cstart_s,
                                                       const int* __restrict__ chist_s,
                                                       int* __restrict__ cnt_src) {
  const int cb = blockIdx.x;
  const int t = threadIdx.x;
  const int cs = cstart_s[cb], cc = chist_s[cb];
  __shared__ int fcnt[256];
  fcnt[t] = 0;
  __syncthreads();
  for (int i = t; i < cc; i += 256) atomicAdd(&fcnt[etmp_s[cs + i]], 1);
  __syncthreads();
  int b = cb * 256 + t;
  if (b < NBUCK) cnt_src[b] = fcnt[t];
}

// ---- fine pass (dst) + integrated h1-source marking ----
__global__ __launch_bounds__(256) void fine_kernel(const int* __restrict__ etmp,
                                                   const int* __restrict__ cstart,
                                                   const int* __restrict__ chist,
                                                   const int* __restrict__ cnt_src,
                                                   const int* __restrict__ qflag,
                                                   int2* __restrict__ scb,
                                                   int2* __restrict__ epay,
                                                   int* __restrict__ mark) {
  const int cb = blockIdx.x;
  const int t = threadIdx.x, lane = t & 63, w = t >> 6;
  const int cs = cstart[cb], cc = chist[cb];
  __shared__ int fcnt[256], fexcl[256], fcur[256];
  fcnt[t] = 0;
  fcur[t] = 0;
  __syncthreads();
  for (int i = t; i < cc; i += 256) atomicAdd(&fcnt[etmp[cs + i] & 255], 1);
  __syncthreads();
  int val = fcnt[t];
  int sc = val;
#pragma unroll
  for (int d = 1; d < 64; d <<= 1) {
    int o = __shfl_up(sc, d);
    if (lane >= d) sc += o;
  }
  __shared__ int wt[4];
  if (lane == 63) wt[w] = sc;
  __syncthreads();
  int woff = 0;
#pragma unroll
  for (int ww = 0; ww < 3; ++ww) woff += (ww < w) ? wt[ww] : 0;
  fexcl[t] = woff + sc - val;
  int b = cb * 256 + t;
  if (b < NBUCK) scb[b] = make_int2(cs + fexcl[t], val);
  __syncthreads();
  for (int i = t; i < cc; i += 256) {
    int e = etmp[cs + i];
    int f = e & 255;
    int src = ((unsigned)e) >> 8;
    int fine = cb * 256 + f;
    int r = fine / NN;
    int dst = fine - r * NN;
    float wgt = rsqrtf((float)cnt_src[r * NN + src]) * rsqrtf((float)fcnt[f]);
    int pos = cs + fexcl[f] + atomicAdd(&fcur[f], 1);
    epay[pos] = make_int2(src, __builtin_bit_cast(int, wgt));
    if (qflag[dst]) mark[src] = 1;   // h1 needed at this source (idempotent store)
  }
}

// ---- compact marked nodes -> list (one atomic per 1024-elem block) ----
__global__ __launch_bounds__(256) void compact_kernel(const int* __restrict__ mark,
                                                      int* __restrict__ list,
                                                      int* __restrict__ cursor) {
  int t = threadIdx.x, lane = t & 63, w = t >> 6;
  int base = blockIdx.x * 1024 + t * 4;
  int loc[4];
  int cnt = 0;
#pragma unroll
  for (int k = 0; k < 4; ++k) {
    int i = base + k;
    if (i < NN && mark[i]) { loc[cnt] = i; ++cnt; }
  }
  int sc = cnt;
#pragma unroll
  for (int d = 1; d < 64; d <<= 1) {
    int o = __shfl_up(sc, d);
    if (lane >= d) sc += o;
  }
  int texcl = sc - cnt;
  __shared__ int wt[4];
  __shared__ int bb;
  if (lane == 63) wt[w] = sc;
  __syncthreads();
  if (t == 0) {
    int tot = wt[0] + wt[1] + wt[2] + wt[3];
    bb = atomicAdd(cursor, tot);
    int a = 0;
#pragma unroll
    for (int ww = 0; ww < 4; ++ww) { int c = wt[ww]; wt[ww] = a; a += c; }
  }
  __syncthreads();
  int p = bb + wt[w] + texcl;
  for (int k = 0; k < cnt; ++k) list[p + k] = loc[k];
}

// ---- aggregate: Z[r][m][f] = sum_{e in bucket(r, nmap[m])} w_e * X[src_e][f] ----
__global__ __launch_bounds__(256) void aggz_kernel(const unsigned short* __restrict__ X,
                                                   const int2* __restrict__ scb,
                                                   const int2* __restrict__ epay,
                                                   const int* __restrict__ nmap,
                                                   const int* __restrict__ cntp,
                                                   unsigned short* __restrict__ Z,
                                                   int Mcap, int Ms) {
  const int count = cntp ? *cntp : Mcap;
  const int r = blockIdx.y;
  const int t = threadIdx.x;
  const int lane = t & 63;
  const int m = blockIdx.x * 16 + (t >> 6) * 4 + (lane >> 4);
  const int j = lane & 15;
  if (m >= count) return;
  int n = nmap ? nmap[m] : m;
  int2 meta = scb[r * NN + n];
  const int2* ep = epay + meta.x;
  const int c = meta.y;

  float ps[8];
#pragma unroll
  for (int k = 0; k < 8; ++k) ps[k] = 0.f;

  int i = 0;
  for (; i + 2 <= c; i += 2) {
    int2 p0 = ep[i], p1 = ep[i + 1];
    float w0 = __builtin_bit_cast(float, p0.y);
    float w1 = __builtin_bit_cast(float, p1.y);
    u16x8 v0 = *reinterpret_cast<const u16x8*>(X + ((size_t)p0.x << 7) + j * 8);
    u16x8 v1 = *reinterpret_cast<const u16x8*>(X + ((size_t)p1.x << 7) + j * 8);
#pragma unroll
    for (int k = 0; k < 8; ++k)
      ps[k] = fmaf(bf2f(v1[k]), w1, fmaf(bf2f(v0[k]), w0, ps[k]));
  }
  if (i < c) {
    int2 p0 = ep[i];
    float w0 = __builtin_bit_cast(float, p0.y);
    u16x8 v0 = *reinterpret_cast<const u16x8*>(X + ((size_t)p0.x << 7) + j * 8);
#pragma unroll
    for (int k = 0; k < 8; ++k) ps[k] = fmaf(bf2f(v0[k]), w0, ps[k]);
  }

  unsigned short tmp[8];
#pragma unroll
  for (int k = 0; k < 8; ++k) tmp[k] = f2bf(ps[k]);
  *reinterpret_cast<u16x8*>(Z + (((size_t)r * Ms + m) << 7) + j * 8) =
      *reinterpret_cast<u16x8*>(tmp);
}

// ---- K=384 GEMM: global_load_lds staging + 2-phase pipeline (R11-proven) ----
#define GBM 128
__global__ __launch_bounds__(512) void gemmp_kernel(const unsigned short* __restrict__ Z,
                                                    const unsigned short* __restrict__ Wt3,
                                                    const float* __restrict__ bsum,
                                                    const int* __restrict__ omap,
                                                    const int* __restrict__ cntp,
                                                    void* __restrict__ outp,
                                                    int M, int Ms, int out_f32) {
  const int count = cntp ? *cntp : M;
  const int m0 = blockIdx.x * GBM;
  if (m0 >= count) return;
  __shared__ unsigned short Abuf[2][GBM * F];   // 2 x 32 KB
  const int t = threadIdx.x;
  const int lane = t & 63, w = t >> 6;
  const int wm = w >> 2, wn = w & 3;            // 2m x 4n wave grid
  const int r0 = lane & 15, kq = lane >> 4;

  fx4 acc[4][2];
#pragma unroll
  for (int mt = 0; mt < 4; ++mt)
#pragma unroll
    for (int nt = 0; nt < 2; ++nt) acc[mt][nt] = (fx4){0.f, 0.f, 0.f, 0.f};

  {
    const unsigned short* Zr = Z + (size_t)m0 * F;
#pragma unroll
    for (int i = 0; i < 4; ++i) {
      int slot = i * 512 + t;
      int row = slot >> 4, s = slot & 15;
      __builtin_amdgcn_global_load_lds(
          (const __attribute__((address_space(1))) uint32_t*)(
              Zr + ((size_t)row << 7) + ((s ^ (row & 7)) << 3)),
          (__attribute__((address_space(3))) uint32_t*)&Abuf[0][slot * 8], 16, 0, 0);
    }
  }
  __syncthreads();

  int cur = 0;
  for (int r = 0; r < NREL; ++r) {
    bf16x8 bfrag[2][4];
    const unsigned short* Wt = Wt3 + (size_t)r * F * F;
#pragma unroll
    for (int nt = 0; nt < 2; ++nt)
#pragma unroll
      for (int kb = 0; kb < 4; ++kb)
        bfrag[nt][kb] = __builtin_bit_cast(bf16x8,
            *reinterpret_cast<const u16x8*>(
                Wt + (wn * 32 + nt * 16 + r0) * F + (4 * kb + kq) * 8));

    if (r + 1 < NREL) {
      const unsigned short* Zr = Z + ((size_t)(r + 1) * Ms + m0) * F;
#pragma unroll
      for (int i = 0; i < 4; ++i) {
        int slot = i * 512 + t;
        int row = slot >> 4, s = slot & 15;
        __builtin_amdgcn_global_load_lds(
            (const __attribute__((address_space(1))) uint32_t*)(
                Zr + ((size_t)row << 7) + ((s ^ (row & 7)) << 3)),
            (__attribute__((address_space(3))) uint32_t*)&Abuf[cur ^ 1][slot * 8],
            16, 0, 0);
      }
    }

#pragma unroll
    for (int kb = 0; kb < 4; ++kb) {
      const int cs = ((kb * 4 + kq) ^ (r0 & 7)) * 8;
      bf16x8 a[4];
#pragma unroll
      for (int mt = 0; mt < 4; ++mt)
        a[mt] = __builtin_bit_cast(bf16x8,
            *reinterpret_cast<const u16x8*>(&Abuf[cur][(wm * 64 + mt * 16 + r0) * F + cs]));
#pragma unroll
      for (int mt = 0; mt < 4; ++mt)
#pragma unroll
        for (int nt = 0; nt < 2; ++nt)
          acc[mt][nt] = __builtin_amdgcn_mfma_f32_16x16x32_bf16(a[mt], bfrag[nt][kb],
                                                                acc[mt][nt], 0, 0, 0);
    }

    __syncthreads();
    cur ^= 1;
  }

#pragma unroll
  for (int mt = 0; mt < 4; ++mt) {
    const int rbase = m0 + wm * 64 + mt * 16 + kq * 4;
#pragma unroll
    for (int nt = 0; nt < 2; ++nt) {
      int col = wn * 32 + nt * 16 + r0;
      float bb = bsum[col];
#pragma unroll
      for (int reg = 0; reg < 4; ++reg) {
        int gm = rbase + reg;
        if (gm < count) {
          float v = tanhf(acc[mt][nt][reg] + bb);
          if (omap) {
            ((unsigned short*)outp)[(size_t)omap[gm] * F + col] = f2bf(v);
          } else if (out_f32) {
            ((float*)outp)[(size_t)gm * F + col] = v;
          } else {
            ((unsigned short*)outp)[(size_t)gm * F + col] = f2bf(v);
          }
        }
      }
    }
  }
}

extern "C" void kernel_launch(void* const* d_in, const int* in_sizes, int n_in,
                              void* d_out, int out_size, void* d_ws, size_t ws_size,
                              hipStream_t stream) {
  const float* emb = (const float*)d_in[0];
  const float* W1  = (const float*)d_in[1];
  const float* b1  = (const float*)d_in[2];
  const float* W2  = (const float*)d_in[3];
  const float* b2  = (const float*)d_in[4];
  const int* e_src = (const int*)d_in[5];
  const int* e_dst = (const int*)d_in[6];
  const int* qsrc  = (const int*)d_in[7];
  const int* qdst  = (const int*)d_in[8];
  float* out = (float*)d_out;

  const int MS1 = ((NN + GBM - 1) / GBM) * GBM;   // 100096 (Z stride/capacity, layer 1)
  const int MQ  = 2 * NQ;                          // 8192

  char* p = (char*)d_ws;
  size_t off = 0;
  auto take = [&](size_t n) { void* q = p + off; off = (off + n + 255) & ~(size_t)255; return q; };
  int* cnt_src  = (int*)take((size_t)NREL * NN * 4);
  int* chist_d  = (int*)take((size_t)NCB * 4);
  int* chist_s  = (int*)take((size_t)NCB * 4);
  int* cstart_d = (int*)take((size_t)NCB * 4);
  int* cstart_s = (int*)take((size_t)NCB * 4);
  int* Hd       = (int*)take((size_t)NCB * CH_BLOCKS * 4);
  int* Hs       = (int*)take((size_t)NCB * CH_BLOCKS * 4);
  int* Hbase_d  = (int*)take((size_t)NCB * CH_BLOCKS * 4);
  int* Hbase_s  = (int*)take((size_t)NCB * CH_BLOCKS * 4);
  int* etmp_d   = (int*)take((size_t)NREL * NE * 4);
  int* etmp_s   = (int*)take((size_t)NREL * NE * 4);
  int2* scb     = (int2*)take((size_t)NBUCK * 8);
  int2* epay    = (int2*)take((size_t)NREL * NE * 8);
  unsigned short* Wtb = (unsigned short*)take(2ull * NREL * F * F * 2);
  float* bsum   = (float*)take(2ull * F * 4);
  int* qnode    = (int*)take((size_t)MQ * 4);
  int* mark     = (int*)take((size_t)NN * 4);
  int* qflag    = (int*)take((size_t)NN * 4);
  int* list     = (int*)take((size_t)NN * 4 + 4);
  int* cursor   = (int*)take(4);
  unsigned short* Xb  = (unsigned short*)take((size_t)NN * F * 2);   // h0 (bf16)
  unsigned short* Xb2 = (unsigned short*)take((size_t)NN * F * 2);   // h1 (bf16, by node id)
  unsigned short* Z   = (unsigned short*)take((size_t)NREL * MS1 * F * 2);

  // 1: merged prep + coarse histograms
  prepch_kernel<<<PREP_BLKS + CH_BLOCKS, 256, 0, stream>>>(
      W1, W2, b1, b2, emb, qsrc, qdst, e_src, e_dst,
      Wtb, bsum, Xb, qnode, mark, qflag, cursor, Hd, Hs);
  // 2-6: atomic-free dual radix bucket build (+qflag set in hsum)
  hsum_kernel<<<(2 * NCB + 3) / 4, 256, 0, stream>>>(Hd, Hs, qnode,
                                                     chist_d, chist_s, qflag);
  cscan_kernel<<<2, 256, 0, stream>>>(chist_d, chist_s, cstart_d, cstart_s);
  {
    dim3 hb(NCB / 4, 2);
    hbase_kernel<<<hb, 256, 0, stream>>>(Hd, Hs, cstart_d, cstart_s, Hbase_d, Hbase_s);
  }
  cscatter_kernel<<<CH_BLOCKS, 256, 0, stream>>>(e_src, e_dst, Hbase_d, Hbase_s,
                                                 etmp_d, etmp_s);
  srccount_kernel<<<NCB, 256, 0, stream>>>(etmp_s, cstart_s, chist_s, cnt_src);
  // 7: fine placement + h1-source marking (mark folded in)
  fine_kernel<<<NCB, 256, 0, stream>>>(etmp_d, cstart_d, chist_d, cnt_src, qflag,
                                       scb, epay, mark);
  // 8: compact marked nodes
  compact_kernel<<<(NN + 1023) / 1024, 256, 0, stream>>>(mark, list, cursor);

  // 9-10: layer 1 on listed nodes only; h1 scattered to Xb2 by node id
  dim3 ag1((NN + 15) / 16, NREL);
  aggz_kernel<<<ag1, 256, 0, stream>>>(Xb, scb, epay, list, cursor, Z, NN, MS1);
  gemmp_kernel<<<MS1 / GBM, 512, 0, stream>>>(Z, Wtb, bsum, list, cursor, Xb2, MS1, MS1, 0);

  // 11-12: layer 2 on the 2*NQ query slots
  dim3 ag2((MQ + 15) / 16, NREL);
  aggz_kernel<<<ag2, 256, 0, stream>>>(Xb2, scb, epay, qnode, nullptr, Z, MQ, MQ);
  gemmp_kernel<<<MQ / GBM, 512, 0, stream>>>(
      Z, Wtb + (size_t)NREL * F * F, bsum + F, nullptr, nullptr, out, MQ, MQ, 1);
}